// Round 1
// baseline (748.708 us; speedup 1.0000x reference)
//
#include <hip/hip_runtime.h>
#include <math.h>

// Problem constants (fixed by setup_inputs)
#define BHX 32          // B*H
#define NN 4096
#define DD 64
#define MM 266
#define MP 272          // padded M (columns 266..271 are zero everywhere)
#define NORMZ 0.35355339059327379f   // 64^-0.25
#define RATIO 0.06131393394849658f   // 266^-0.5
#define EPSV 1e-4f
#define NEG_INF (-3.4e38f)

// ---------------------------------------------------------------------------
// dd kernel: computes dd[r][m] = sum_k (NORMZ*data[r][k]) * proj[m][k] for a
// 64-row x 272-col tile.  MODE 0: block max of dd (k stab pass).
// MODE 1: kp = RATIO*(exp(dd - diag - stab)+eps), write kp + atomic kc.
// MODE 2: qp = RATIO*(exp(dd - diag - rowmax)+eps), write qp.
// block 256 = 16(tr: 4 rows each) x 16(tc); acc[4][17]:
//   cols c<16: m = 64*(c>>2) + 4*tc + (c&3)   (always < 256, valid)
//   col c==16: m = 256 + tc                    (valid iff tc < 10)
// ---------------------------------------------------------------------------
template <int MODE>
__launch_bounds__(256, 2)
__global__ void dd_kernel(const float* __restrict__ data,
                          const float* __restrict__ proj,
                          float* __restrict__ outp,
                          float* __restrict__ partmax,
                          const float* __restrict__ stabp,
                          float* __restrict__ kc)
{
    __shared__ __align__(16) float dataT[64][68];    // [k][r], stride 68 for b128-aligned reads
    __shared__ __align__(16) float projT[64][148];   // [k][m-chunk], stride 148 (4-mod-32 -> ok)
    __shared__ float diagL[64];

    const int t  = threadIdx.x;
    const int tr = t >> 4;          // 0..15
    const int tc = t & 15;          // 0..15
    const int hd   = blockIdx.y;
    const int row0 = blockIdx.x << 6;

    const float* dbase = data + ((size_t)hd * NN + row0) * DD;

    // stage dataT[k][r] = NORMZ * data[r][k]   (coalesced global, 8-way LDS write conflict ok)
    #pragma unroll
    for (int j = 0; j < 16; ++j) {
        int i = t + j * 256;            // i = r*64 + kk
        int r = i >> 6, kk = i & 63;
        dataT[kk][r] = dbase[i] * NORMZ;
    }
    __syncthreads();

    if (MODE != 0 && t < 64) {
        float s = 0.f;
        #pragma unroll
        for (int kk = 0; kk < 64; ++kk) { float x = dataT[kk][t]; s += x * x; }
        diagL[t] = 0.5f * s;            // 0.5 * norm^2 * sum(data^2)
    }

    float acc[4][17];
    #pragma unroll
    for (int i = 0; i < 4; ++i)
        #pragma unroll
        for (int c = 0; c < 17; ++c) acc[i][c] = 0.f;

    // ---------------- chunk 0: m in [0,128) ----------------
    #pragma unroll
    for (int j = 0; j < 32; ++j) {
        int i = t + j * 256;            // i = m*64 + kk, m<128
        int m = i >> 6, kk = i & 63;
        projT[kk][m] = proj[i];
    }
    __syncthreads();

    for (int kk = 0; kk < 64; ++kk) {
        const float4 av = *(const float4*)&dataT[kk][tr << 2];
        const float A[4] = {av.x, av.y, av.z, av.w};
        #pragma unroll
        for (int g = 0; g < 2; ++g) {
            const float4 bv = *(const float4*)&projT[kk][(g << 6) + (tc << 2)];
            const float B[4] = {bv.x, bv.y, bv.z, bv.w};
            const int c0 = g << 2;
            #pragma unroll
            for (int i = 0; i < 4; ++i)
                #pragma unroll
                for (int jj = 0; jj < 4; ++jj)
                    acc[i][c0 + jj] += A[i] * B[jj];
        }
    }
    __syncthreads();

    // ---------------- chunk 1: m in [128,272), width 144 ----------------
    #pragma unroll
    for (int j = 0; j < 36; ++j) {
        int i = t + j * 256;            // i = mloc*64 + kk, mloc<144
        int mloc = i >> 6, kk = i & 63;
        int m = 128 + mloc;
        projT[kk][mloc] = (m < MM) ? proj[m * 64 + kk] : 0.f;
    }
    __syncthreads();

    for (int kk = 0; kk < 64; ++kk) {
        const float4 av = *(const float4*)&dataT[kk][tr << 2];
        const float A[4] = {av.x, av.y, av.z, av.w};
        #pragma unroll
        for (int g = 0; g < 2; ++g) {
            const float4 bv = *(const float4*)&projT[kk][(g << 6) + (tc << 2)];
            const float B[4] = {bv.x, bv.y, bv.z, bv.w};
            const int c0 = 8 + (g << 2);
            #pragma unroll
            for (int i = 0; i < 4; ++i)
                #pragma unroll
                for (int jj = 0; jj < 4; ++jj)
                    acc[i][c0 + jj] += A[i] * B[jj];
        }
        const float bs = projT[kk][128 + tc];   // m = 256+tc
        #pragma unroll
        for (int i = 0; i < 4; ++i) acc[i][16] += A[i] * bs;
    }
    __syncthreads();     // projT now reusable as scratch

    float* scratch = &projT[0][0];

    if (MODE == 0) {
        float mx = NEG_INF;
        #pragma unroll
        for (int i = 0; i < 4; ++i) {
            #pragma unroll
            for (int c = 0; c < 16; ++c) mx = fmaxf(mx, acc[i][c]);
            if (tc < 10) mx = fmaxf(mx, acc[i][16]);
        }
        scratch[t] = mx;
        __syncthreads();
        for (int s = 128; s > 0; s >>= 1) {
            if (t < s) scratch[t] = fmaxf(scratch[t], scratch[t + s]);
            __syncthreads();
        }
        if (t == 0) partmax[blockIdx.y * 64 + blockIdx.x] = scratch[0];
        return;
    }

    if (MODE == 2) {
        // row max (exclude padded cols) -> rowC = diag + rowmax stored in diagL
        float* redL = scratch;               // [16][68] as [tc][r]
        #pragma unroll
        for (int i = 0; i < 4; ++i) {
            float mx = NEG_INF;
            #pragma unroll
            for (int c = 0; c < 16; ++c) mx = fmaxf(mx, acc[i][c]);
            if (tc < 10) mx = fmaxf(mx, acc[i][16]);
            redL[tc * 68 + (tr << 2) + i] = mx;
        }
        __syncthreads();
        if (t < 64) {
            float m2 = redL[t];
            #pragma unroll
            for (int j = 1; j < 16; ++j) m2 = fmaxf(m2, redL[j * 68 + t]);
            diagL[t] += m2;
        }
        __syncthreads();
    }

    const float stab = (MODE == 1) ? *stabp : 0.f;
    float* outbase = outp + ((size_t)hd * NN + row0) * MP;

    #pragma unroll
    for (int i = 0; i < 4; ++i) {
        const int r = (tr << 2) + i;
        const float dg = diagL[r] + stab;    // MODE2: diagL already holds diag+rowmax, stab=0
        #pragma unroll
        for (int c = 0; c < 17; ++c) {
            bool valid = (c < 16) || (tc < 10);
            acc[i][c] = valid ? (RATIO * (__expf(acc[i][c] - dg) + EPSV)) : 0.f;
        }
        float* orow = outbase + (size_t)r * MP;
        #pragma unroll
        for (int g = 0; g < 4; ++g) {
            float4 sv = make_float4(acc[i][(g << 2) + 0], acc[i][(g << 2) + 1],
                                    acc[i][(g << 2) + 2], acc[i][(g << 2) + 3]);
            *(float4*)&orow[(g << 6) + (tc << 2)] = sv;
        }
        orow[256 + tc] = acc[i][16];
    }

    if (MODE == 1) {
        // kc partial column sums over this 64-row tile
        float* kcp = scratch;                // [16][272] as [tr][col]
        #pragma unroll
        for (int c = 0; c < 17; ++c) {
            int col = (c < 16) ? (((c >> 2) << 6) + (tc << 2) + (c & 3)) : (256 + tc);
            kcp[tr * 272 + col] = acc[0][c] + acc[1][c] + acc[2][c] + acc[3][c];
        }
        __syncthreads();
        for (int col = t; col < 272; col += 256) {
            float s = 0.f;
            #pragma unroll
            for (int j = 0; j < 16; ++j) s += kcp[j * 272 + col];
            atomicAdd(&kc[hd * MP + col], s);
        }
    }
}

// ---------------------------------------------------------------------------
__global__ void reduce_max_kernel(const float* __restrict__ partmax,
                                  float* __restrict__ stab, int n)
{
    __shared__ float sm[256];
    const int t = threadIdx.x;
    float mx = NEG_INF;
    for (int i = t; i < n; i += 256) mx = fmaxf(mx, partmax[i]);
    sm[t] = mx;
    __syncthreads();
    for (int s = 128; s > 0; s >>= 1) {
        if (t < s) sm[t] = fmaxf(sm[t], sm[t + s]);
        __syncthreads();
    }
    if (t == 0) *stab = sm[0];
}

// ---------------------------------------------------------------------------
// ctx kernel: ctx[hd][m][e] += sum_n kp[hd][n][m] * v[hd][n][e]
// grid (16 n-chunks of 256, 32 heads); block 256 = 16(tm) x 16(te)
// acc[17][4]; fp32 atomics into global ctx (zeroed beforehand).
// ---------------------------------------------------------------------------
__launch_bounds__(256, 2)
__global__ void ctx_kernel(const float* __restrict__ kp,
                           const float* __restrict__ v,
                           float* __restrict__ ctx)
{
    __shared__ __align__(16) float kpL[32][272];
    __shared__ __align__(16) float vL[32][68];

    const int t  = threadIdx.x;
    const int tm = t >> 4, te = t & 15;
    const int hd = blockIdx.y;
    const int n0 = blockIdx.x << 8;

    float acc[17][4];
    #pragma unroll
    for (int c = 0; c < 17; ++c)
        #pragma unroll
        for (int jj = 0; jj < 4; ++jj) acc[c][jj] = 0.f;

    for (int it = 0; it < 8; ++it) {
        const float* kpb = kp + ((size_t)hd * NN + n0 + (it << 5)) * MP;
        #pragma unroll
        for (int j = 0; j < 34; ++j) {            // 32*272/256
            int i = t + j * 256;
            kpL[i / 272][i % 272] = kpb[i];
        }
        const float* vb = v + ((size_t)hd * NN + n0 + (it << 5)) * DD;
        #pragma unroll
        for (int j = 0; j < 8; ++j) {
            int i = t + j * 256;
            vL[i >> 6][i & 63] = vb[i];
        }
        __syncthreads();

        for (int row = 0; row < 32; ++row) {
            const float4 bv = *(const float4*)&vL[row][te << 2];
            const float B[4] = {bv.x, bv.y, bv.z, bv.w};
            float A[17];
            #pragma unroll
            for (int g = 0; g < 4; ++g) {
                const float4 a4 = *(const float4*)&kpL[row][(g << 6) + (tm << 2)];
                A[(g << 2) + 0] = a4.x; A[(g << 2) + 1] = a4.y;
                A[(g << 2) + 2] = a4.z; A[(g << 2) + 3] = a4.w;
            }
            A[16] = kpL[row][256 + tm];
            #pragma unroll
            for (int c = 0; c < 17; ++c)
                #pragma unroll
                for (int jj = 0; jj < 4; ++jj)
                    acc[c][jj] += A[c] * B[jj];
        }
        __syncthreads();
    }

    float* cb = ctx + (size_t)hd * MP * DD;
    #pragma unroll
    for (int c = 0; c < 17; ++c) {
        int m = (c < 16) ? (((c >> 2) << 6) + (tm << 2) + (c & 3)) : (256 + tm);
        #pragma unroll
        for (int jj = 0; jj < 4; ++jj)
            atomicAdd(&cb[m * DD + (te << 2) + jj], acc[c][jj]);
    }
}

// ---------------------------------------------------------------------------
// out kernel: out[n][e] = (sum_m qp[n][m]*ctx[m][e]) / (sum_m qp[n][m]*kc[m])
// grid (32 row-tiles of 128, 32 heads); block 256 = 16(tr: 8 rows) x 16(tc: 4 e)
// K staged in 4 chunks of 68 (qp transposed into LDS).
// ---------------------------------------------------------------------------
__launch_bounds__(256, 2)
__global__ void out_kernel(const float* __restrict__ qp,
                           const float* __restrict__ ctx,
                           const float* __restrict__ kc,
                           float* __restrict__ out)
{
    __shared__ __align__(16) float qpT[68][132];   // [m][r]
    __shared__ __align__(16) float ctxL[68][68];   // [m][e]
    __shared__ float kcL[68];
    __shared__ float denL[128];

    const int t  = threadIdx.x;
    const int tr = t >> 4, tc = t & 15;
    const int hd = blockIdx.y;
    const int n0 = blockIdx.x << 7;

    float acc[8][4];
    #pragma unroll
    for (int i = 0; i < 8; ++i)
        #pragma unroll
        for (int jj = 0; jj < 4; ++jj) acc[i][jj] = 0.f;
    if (t < 128) denL[t] = 0.f;

    const float* qpb = qp + ((size_t)hd * NN + n0) * MP;

    for (int c4 = 0; c4 < 4; ++c4) {
        const int mb = c4 * 68;
        #pragma unroll
        for (int j = 0; j < 34; ++j) {            // 128*68/256
            int i = t + j * 256;
            int r = i / 68, m = i % 68;
            qpT[m][r] = qpb[(size_t)r * MP + mb + m];
        }
        const float* cxb = ctx + ((size_t)hd * MP + mb) * DD;
        #pragma unroll
        for (int j = 0; j < 17; ++j) {            // 68*64/256
            int i = t + j * 256;
            ctxL[i >> 6][i & 63] = cxb[i];
        }
        if (t < 68) kcL[t] = kc[hd * MP + mb + t];
        __syncthreads();

        if (t < 128) {                            // denominator partial for row t
            float s = 0.f;
            for (int m = 0; m < 68; ++m) s += qpT[m][t] * kcL[m];
            denL[t] += s;
        }

        for (int m = 0; m < 68; ++m) {
            const float4 a0 = *(const float4*)&qpT[m][tr << 3];
            const float4 a1 = *(const float4*)&qpT[m][(tr << 3) + 4];
            const float A[8] = {a0.x, a0.y, a0.z, a0.w, a1.x, a1.y, a1.z, a1.w};
            const float4 bv = *(const float4*)&ctxL[m][tc << 2];
            const float B[4] = {bv.x, bv.y, bv.z, bv.w};
            #pragma unroll
            for (int i = 0; i < 8; ++i)
                #pragma unroll
                for (int jj = 0; jj < 4; ++jj)
                    acc[i][jj] += A[i] * B[jj];
        }
        __syncthreads();
    }

    float* ob = out + ((size_t)hd * NN + n0) * DD;
    #pragma unroll
    for (int i = 0; i < 8; ++i) {
        const int r = (tr << 3) + i;
        const float dinv = 1.0f / denL[r];
        float4 sv = make_float4(acc[i][0] * dinv, acc[i][1] * dinv,
                                acc[i][2] * dinv, acc[i][3] * dinv);
        *(float4*)&ob[(size_t)r * DD + (tc << 2)] = sv;
    }
}

// ---------------------------------------------------------------------------
extern "C" void kernel_launch(void* const* d_in, const int* in_sizes, int n_in,
                              void* d_out, int out_size, void* d_ws, size_t ws_size,
                              hipStream_t stream)
{
    const float* q    = (const float*)d_in[0];
    const float* k    = (const float*)d_in[1];
    const float* v    = (const float*)d_in[2];
    const float* proj = (const float*)d_in[3];
    float* out = (float*)d_out;
    float* ws  = (float*)d_ws;

    const size_t SZP = (size_t)BHX * NN * MP;      // 35,651,584 floats (kp, later reused as qp)
    float* kpb  = ws;
    float* ctx  = ws + SZP;                        // [BHX][MP][64]
    float* kc   = ctx + (size_t)BHX * MP * DD;     // [BHX][MP]
    float* pmax = kc + BHX * MP;                   // [2048]
    float* stab = pmax + 2048;                     // [1]

    // zero ctx + kc (accumulated via atomics)
    hipMemsetAsync(ctx, 0, ((size_t)BHX * MP * DD + BHX * MP) * sizeof(float), stream);

    dim3 blk(256);
    // 1) global max of dd_k
    dd_kernel<0><<<dim3(64, 32), blk, 0, stream>>>(k, proj, nullptr, pmax, nullptr, nullptr);
    reduce_max_kernel<<<1, 256, 0, stream>>>(pmax, stab, 2048);
    // 2) kp + kc
    dd_kernel<1><<<dim3(64, 32), blk, 0, stream>>>(k, proj, kpb, nullptr, stab, kc);
    // 3) ctx = kp^T @ v
    ctx_kernel<<<dim3(16, 32), blk, 0, stream>>>(kpb, v, ctx);
    // 4) qp (reuses kp buffer; kp no longer needed)
    dd_kernel<2><<<dim3(64, 32), blk, 0, stream>>>(q, proj, kpb, nullptr, nullptr, nullptr);
    // 5) out = (qp @ ctx) * 1/(qp . kc)
    out_kernel<<<dim3(32, 32), blk, 0, stream>>>(kpb, ctx, kc, out);
}

// Round 2
// 688.582 us; speedup vs baseline: 1.0873x; 1.0873x over previous
//
#include <hip/hip_runtime.h>
#include <math.h>

// Problem constants (fixed by setup_inputs)
#define BHX 32          // B*H
#define NN 4096
#define DD 64
#define MM 266
#define MP 272          // padded M (columns 266..271 are zero everywhere)
#define NORMZ 0.35355339059327379f   // 64^-0.25
#define RATIO 0.06131393394849658f   // 266^-0.5
#define EPSV 1e-4f
#define NEG_INF (-3.4e38f)

// ===========================================================================
// Fused k-side pass:
//   per 128-row k-tile: dd = (NORMZ*k) @ proj^T  (64x272 subtiles),
//   u = exp(dd - diag) (unstabilized; stab applied later as scalar),
//   block max of dd -> pmax,  ctx' += u^T @ v (atomics),  kc' += colsum(u),
//   vsum += colsum(v).
// block 256 = 16(tr) x 16(tc); grid (32 chunks, 32 heads).
// ===========================================================================
__launch_bounds__(256, 2)
__global__ void kpass_kernel(const float* __restrict__ k,
                             const float* __restrict__ v,
                             const float* __restrict__ proj,
                             float* __restrict__ ctxr,
                             float* __restrict__ kcr,
                             float* __restrict__ vsum,
                             float* __restrict__ pmax)
{
    __shared__ __align__(16) float dataT[64][68];   // [kk][r]
    __shared__ __align__(16) float region2[9472];   // projT[64][148]  OR  uL[32][272]
    __shared__ __align__(16) float vL[32][68];
    __shared__ float diagL[64];
    __shared__ float redL[256];

    float (*projT)[148] = (float(*)[148])region2;
    float (*uL)[272]    = (float(*)[272])region2;

    const int t  = threadIdx.x;
    const int tr = t >> 4;          // 0..15
    const int tc = t & 15;          // 0..15
    const int hd   = blockIdx.y;
    const int row0 = blockIdx.x << 7;   // 128 rows per block

    float acc2[17][4];
    #pragma unroll
    for (int c = 0; c < 17; ++c)
        #pragma unroll
        for (int jj = 0; jj < 4; ++jj) acc2[c][jj] = 0.f;
    float kc_acc0 = 0.f, kc_acc1 = 0.f, vs_acc = 0.f;
    float bmax = NEG_INF;

    for (int it = 0; it < 2; ++it) {
        const int r0 = row0 + (it << 6);
        const float* dbase = k + ((size_t)hd * NN + r0) * DD;

        // ---- stage dataT (k-rows, transposed) + projT chunk0 ----
        #pragma unroll
        for (int j = 0; j < 16; ++j) {
            int i = t + (j << 8);           // i = r*64 + kk
            dataT[i & 63][i >> 6] = dbase[i] * NORMZ;
        }
        #pragma unroll
        for (int j = 0; j < 32; ++j) {
            int i = t + (j << 8);           // i = m*64 + kk, m<128
            projT[i & 63][i >> 6] = proj[i];
        }
        __syncthreads();

        if (t < 64) {
            float s = 0.f;
            #pragma unroll
            for (int kk = 0; kk < 64; ++kk) { float x = dataT[kk][t]; s += x * x; }
            diagL[t] = 0.5f * s;
        }

        float acc[4][17];
        #pragma unroll
        for (int i = 0; i < 4; ++i)
            #pragma unroll
            for (int c = 0; c < 17; ++c) acc[i][c] = 0.f;

        // ---- GEMM1 chunk0: m in [0,128) ----
        for (int kk = 0; kk < 64; ++kk) {
            const float4 av = *(const float4*)&dataT[kk][tr << 2];
            const float A[4] = {av.x, av.y, av.z, av.w};
            #pragma unroll
            for (int g = 0; g < 2; ++g) {
                const float4 bv = *(const float4*)&projT[kk][(g << 6) + (tc << 2)];
                const float B[4] = {bv.x, bv.y, bv.z, bv.w};
                const int c0 = g << 2;
                #pragma unroll
                for (int i = 0; i < 4; ++i)
                    #pragma unroll
                    for (int jj = 0; jj < 4; ++jj)
                        acc[i][c0 + jj] += A[i] * B[jj];
            }
        }
        __syncthreads();

        // ---- stage projT chunk1: m in [128,272) ----
        #pragma unroll
        for (int j = 0; j < 36; ++j) {
            int i = t + (j << 8);           // i = mloc*64 + kk, mloc<144
            int mloc = i >> 6, kk = i & 63;
            int m = 128 + mloc;
            projT[kk][mloc] = (m < MM) ? proj[m * 64 + kk] : 0.f;
        }
        __syncthreads();

        for (int kk = 0; kk < 64; ++kk) {
            const float4 av = *(const float4*)&dataT[kk][tr << 2];
            const float A[4] = {av.x, av.y, av.z, av.w};
            #pragma unroll
            for (int g = 0; g < 2; ++g) {
                const float4 bv = *(const float4*)&projT[kk][(g << 6) + (tc << 2)];
                const float B[4] = {bv.x, bv.y, bv.z, bv.w};
                const int c0 = 8 + (g << 2);
                #pragma unroll
                for (int i = 0; i < 4; ++i)
                    #pragma unroll
                    for (int jj = 0; jj < 4; ++jj)
                        acc[i][c0 + jj] += A[i] * B[jj];
            }
            const float bs = projT[kk][128 + tc];   // m = 256+tc
            #pragma unroll
            for (int i = 0; i < 4; ++i) acc[i][16] += A[i] * bs;
        }

        // ---- block max of dd (valid cols only) ----
        {
            float mx = NEG_INF;
            #pragma unroll
            for (int i = 0; i < 4; ++i) {
                #pragma unroll
                for (int c = 0; c < 16; ++c) mx = fmaxf(mx, acc[i][c]);
                if (tc < 10) mx = fmaxf(mx, acc[i][16]);
            }
            redL[t] = mx;
            __syncthreads();
            for (int sft = 128; sft > 0; sft >>= 1) {
                if (t < sft) redL[t] = fmaxf(redL[t], redL[t + sft]);
                __syncthreads();
            }
            if (t == 0) bmax = fmaxf(bmax, redL[0]);
        }

        // ---- u = exp(dd - diag), zero invalid cols ----
        #pragma unroll
        for (int i = 0; i < 4; ++i) {
            const float dg = diagL[(tr << 2) + i];
            #pragma unroll
            for (int c = 0; c < 17; ++c) {
                bool valid = (c < 16) || (tc < 10);
                acc[i][c] = valid ? __expf(acc[i][c] - dg) : 0.f;
            }
        }

        // ---- two 32-row subtiles: u^T @ v into acc2 ----
        for (int s = 0; s < 2; ++s) {
            if ((tr >> 3) == s) {
                const int rl = (tr & 7) << 2;
                #pragma unroll
                for (int i = 0; i < 4; ++i) {
                    #pragma unroll
                    for (int g = 0; g < 4; ++g)
                        *(float4*)&uL[rl + i][(g << 6) + (tc << 2)] =
                            make_float4(acc[i][(g << 2) + 0], acc[i][(g << 2) + 1],
                                        acc[i][(g << 2) + 2], acc[i][(g << 2) + 3]);
                    uL[rl + i][256 + tc] = acc[i][16];
                }
            }
            const float* vb = v + ((size_t)hd * NN + r0 + (s << 5)) * DD;
            #pragma unroll
            for (int j = 0; j < 8; ++j) {
                int i2 = t + (j << 8);
                vL[i2 >> 6][i2 & 63] = vb[i2];
            }
            __syncthreads();

            if (t < 64) {
                float sv = 0.f;
                #pragma unroll
                for (int r = 0; r < 32; ++r) sv += vL[r][t];
                vs_acc += sv;
            }

            for (int r = 0; r < 32; ++r) {
                const float4 bv = *(const float4*)&vL[r][tc << 2];
                const float B[4] = {bv.x, bv.y, bv.z, bv.w};
                float A[17];
                #pragma unroll
                for (int g = 0; g < 4; ++g) {
                    const float4 a4 = *(const float4*)&uL[r][(g << 6) + (tr << 2)];
                    A[(g << 2) + 0] = a4.x; A[(g << 2) + 1] = a4.y;
                    A[(g << 2) + 2] = a4.z; A[(g << 2) + 3] = a4.w;
                }
                A[16] = uL[r][256 + tr];
                #pragma unroll
                for (int c = 0; c < 17; ++c)
                    #pragma unroll
                    for (int jj = 0; jj < 4; ++jj)
                        acc2[c][jj] += A[c] * B[jj];
            }

            // kc' column partial sums
            {
                float sk = 0.f;
                #pragma unroll
                for (int r = 0; r < 32; ++r) sk += uL[r][t];
                kc_acc0 += sk;
                if (t < 16) {
                    float sk1 = 0.f;
                    #pragma unroll
                    for (int r = 0; r < 32; ++r) sk1 += uL[r][256 + t];
                    kc_acc1 += sk1;
                }
            }
            __syncthreads();
        }
    }

    // ---- epilogue: atomics ----
    if (t == 0) pmax[blockIdx.y * 32 + blockIdx.x] = bmax;

    float* cb = ctxr + (size_t)hd * MP * DD;
    #pragma unroll
    for (int c = 0; c < 17; ++c) {
        int m = (c < 16) ? (((c >> 2) << 6) + (tr << 2) + (c & 3)) : (256 + tr);
        #pragma unroll
        for (int jj = 0; jj < 4; ++jj)
            atomicAdd(&cb[m * DD + (tc << 2) + jj], acc2[c][jj]);
    }
    atomicAdd(&kcr[hd * MP + t], kc_acc0);
    if (t < 16) atomicAdd(&kcr[hd * MP + 256 + t], kc_acc1);
    if (t < 64) atomicAdd(&vsum[hd * DD + t], vs_acc);
}

// ---------------------------------------------------------------------------
__global__ void reduce_max_kernel(const float* __restrict__ partmax,
                                  float* __restrict__ stab, int n)
{
    __shared__ float sm[256];
    const int t = threadIdx.x;
    float mx = NEG_INF;
    for (int i = t; i < n; i += 256) mx = fmaxf(mx, partmax[i]);
    sm[t] = mx;
    __syncthreads();
    for (int s = 128; s > 0; s >>= 1) {
        if (t < s) sm[t] = fmaxf(sm[t], sm[t + s]);
        __syncthreads();
    }
    if (t == 0) *stab = sm[0];
}

// ===========================================================================
// Fused q-side pass:
//   per 64-row q-tile: dd = (NORMZ*q) @ proj^T, rowmax, qp = ratio*(exp(dd-
//   diag-rowmax)+eps) in regs; denominator via staged kc_final; then 5 m-chunks:
//   LDS-transpose qp chunk + stage finalized ctx chunk, GEMM out-tile; divide.
// block 256 = 16(tr: 4 rows) x 16(tc); grid (64 chunks, 32 heads).
// ===========================================================================
__launch_bounds__(256, 2)
__global__ void qpass_kernel(const float* __restrict__ q,
                             const float* __restrict__ proj,
                             const float* __restrict__ ctxr,
                             const float* __restrict__ kcr,
                             const float* __restrict__ vsum,
                             const float* __restrict__ stabp,
                             float* __restrict__ out)
{
    __shared__ __align__(16) float dataT[64][68];
    __shared__ __align__(16) float region2[9472];   // projT[64][148] OR qpT[64][68]+ctxL[64][64]
    __shared__ float kcF[MP];
    __shared__ float vsumL[64];
    __shared__ float diagL[64];
    __shared__ float redL[16 * 68];
    __shared__ float denF[64];

    float (*projT)[148] = (float(*)[148])region2;
    float (*qpT)[68]    = (float(*)[68])region2;                 // [ml][r]
    float (*ctxL)[64]   = (float(*)[64])(region2 + 4352);        // [ml][e]

    const int t  = threadIdx.x;
    const int tr = t >> 4;
    const int tc = t & 15;
    const int hd   = blockIdx.y;
    const int row0 = blockIdx.x << 6;   // 64 rows per block

    const float stab = *stabp;
    const float Asc  = RATIO * __expf(-stab);
    const float REPS = RATIO * EPSV;

    // stage kc_final + vsum
    kcF[t] = Asc * kcr[hd * MP + t] + REPS * (float)NN;
    if (t < 16) kcF[256 + t] = Asc * kcr[hd * MP + 256 + t] + REPS * (float)NN;
    if (t < 64) vsumL[t] = vsum[hd * DD + t];

    const float* dbase = q + ((size_t)hd * NN + row0) * DD;
    #pragma unroll
    for (int j = 0; j < 16; ++j) {
        int i = t + (j << 8);
        dataT[i & 63][i >> 6] = dbase[i] * NORMZ;
    }
    #pragma unroll
    for (int j = 0; j < 32; ++j) {
        int i = t + (j << 8);
        projT[i & 63][i >> 6] = proj[i];
    }
    __syncthreads();

    if (t < 64) {
        float s = 0.f;
        #pragma unroll
        for (int kk = 0; kk < 64; ++kk) { float x = dataT[kk][t]; s += x * x; }
        diagL[t] = 0.5f * s;
    }

    float acc[4][17];
    #pragma unroll
    for (int i = 0; i < 4; ++i)
        #pragma unroll
        for (int c = 0; c < 17; ++c) acc[i][c] = 0.f;

    for (int kk = 0; kk < 64; ++kk) {
        const float4 av = *(const float4*)&dataT[kk][tr << 2];
        const float A[4] = {av.x, av.y, av.z, av.w};
        #pragma unroll
        for (int g = 0; g < 2; ++g) {
            const float4 bv = *(const float4*)&projT[kk][(g << 6) + (tc << 2)];
            const float B[4] = {bv.x, bv.y, bv.z, bv.w};
            const int c0 = g << 2;
            #pragma unroll
            for (int i = 0; i < 4; ++i)
                #pragma unroll
                for (int jj = 0; jj < 4; ++jj)
                    acc[i][c0 + jj] += A[i] * B[jj];
        }
    }
    __syncthreads();

    #pragma unroll
    for (int j = 0; j < 36; ++j) {
        int i = t + (j << 8);
        int mloc = i >> 6, kk = i & 63;
        int m = 128 + mloc;
        projT[kk][mloc] = (m < MM) ? proj[m * 64 + kk] : 0.f;
    }
    __syncthreads();

    for (int kk = 0; kk < 64; ++kk) {
        const float4 av = *(const float4*)&dataT[kk][tr << 2];
        const float A[4] = {av.x, av.y, av.z, av.w};
        #pragma unroll
        for (int g = 0; g < 2; ++g) {
            const float4 bv = *(const float4*)&projT[kk][(g << 6) + (tc << 2)];
            const float B[4] = {bv.x, bv.y, bv.z, bv.w};
            const int c0 = 8 + (g << 2);
            #pragma unroll
            for (int i = 0; i < 4; ++i)
                #pragma unroll
                for (int jj = 0; jj < 4; ++jj)
                    acc[i][c0 + jj] += A[i] * B[jj];
        }
        const float bs = projT[kk][128 + tc];
        #pragma unroll
        for (int i = 0; i < 4; ++i) acc[i][16] += A[i] * bs;
    }

    // ---- rowmax (valid cols) -> diagL holds diag + rowmax ----
    #pragma unroll
    for (int i = 0; i < 4; ++i) {
        float mx = NEG_INF;
        #pragma unroll
        for (int c = 0; c < 16; ++c) mx = fmaxf(mx, acc[i][c]);
        if (tc < 10) mx = fmaxf(mx, acc[i][16]);
        redL[tc * 68 + (tr << 2) + i] = mx;
    }
    __syncthreads();
    if (t < 64) {
        float m2 = redL[t];
        #pragma unroll
        for (int j = 1; j < 16; ++j) m2 = fmaxf(m2, redL[j * 68 + t]);
        diagL[t] += m2;
    }
    __syncthreads();

    // ---- qp = ratio*(exp(dd - (diag+rowmax)) + eps), zero invalid ----
    #pragma unroll
    for (int i = 0; i < 4; ++i) {
        const float dg = diagL[(tr << 2) + i];
        #pragma unroll
        for (int c = 0; c < 17; ++c) {
            bool valid = (c < 16) || (tc < 10);
            acc[i][c] = valid ? (RATIO * (__expf(acc[i][c] - dg) + EPSV)) : 0.f;
        }
    }

    // ---- denominator: den_r = sum_m qp[r][m]*kcF[m] ----
    #pragma unroll
    for (int i = 0; i < 4; ++i) {
        float d = 0.f;
        #pragma unroll
        for (int c = 0; c < 16; ++c)
            d += acc[i][c] * kcF[((c >> 2) << 6) + (tc << 2) + (c & 3)];
        d += acc[i][16] * kcF[256 + tc];
        redL[tc * 68 + (tr << 2) + i] = d;
    }
    __syncthreads();
    if (t < 64) {
        float d = 0.f;
        #pragma unroll
        for (int j = 0; j < 16; ++j) d += redL[j * 68 + t];
        denF[t] = d;
    }
    __syncthreads();

    // ---- out-tile GEMM over 5 m-chunks ----
    float acc3[4][4];
    #pragma unroll
    for (int i = 0; i < 4; ++i)
        #pragma unroll
        for (int jj = 0; jj < 4; ++jj) acc3[i][jj] = 0.f;

    for (int g = 0; g < 4; ++g) {
        // transpose qp chunk into qpT[ml][r]
        #pragma unroll
        for (int d = 0; d < 4; ++d)
            *(float4*)&qpT[(tc << 2) + d][tr << 2] =
                make_float4(acc[0][(g << 2) + d], acc[1][(g << 2) + d],
                            acc[2][(g << 2) + d], acc[3][(g << 2) + d]);
        // stage finalized ctx chunk: ctx = Asc*ctx' + REPS*vsum
        const float* cxb = ctxr + ((size_t)hd * MP + (g << 6)) * DD;
        #pragma unroll
        for (int j = 0; j < 16; ++j) {
            int i2 = t + (j << 8);
            ctxL[i2 >> 6][i2 & 63] = Asc * cxb[i2] + REPS * vsumL[i2 & 63];
        }
        __syncthreads();
        for (int ml = 0; ml < 64; ++ml) {
            const float4 a4 = *(const float4*)&qpT[ml][tr << 2];
            const float A[4] = {a4.x, a4.y, a4.z, a4.w};
            const float4 b4 = *(const float4*)&ctxL[ml][tc << 2];
            const float B[4] = {b4.x, b4.y, b4.z, b4.w};
            #pragma unroll
            for (int i = 0; i < 4; ++i)
                #pragma unroll
                for (int jj = 0; jj < 4; ++jj)
                    acc3[i][jj] += A[i] * B[jj];
        }
        __syncthreads();
    }
    // chunk 4: m in [256,272)
    {
        *(float4*)&qpT[tc][tr << 2] =
            make_float4(acc[0][16], acc[1][16], acc[2][16], acc[3][16]);
        const float* cxb = ctxr + ((size_t)hd * MP + 256) * DD;
        #pragma unroll
        for (int j = 0; j < 4; ++j) {
            int i2 = t + (j << 8);
            ctxL[i2 >> 6][i2 & 63] = Asc * cxb[i2] + REPS * vsumL[i2 & 63];
        }
        __syncthreads();
        for (int ml = 0; ml < 16; ++ml) {
            const float4 a4 = *(const float4*)&qpT[ml][tr << 2];
            const float A[4] = {a4.x, a4.y, a4.z, a4.w};
            const float4 b4 = *(const float4*)&ctxL[ml][tc << 2];
            const float B[4] = {b4.x, b4.y, b4.z, b4.w};
            #pragma unroll
            for (int i = 0; i < 4; ++i)
                #pragma unroll
                for (int jj = 0; jj < 4; ++jj)
                    acc3[i][jj] += A[i] * B[jj];
        }
    }

    float* ob = out + ((size_t)hd * NN + row0) * DD;
    #pragma unroll
    for (int i = 0; i < 4; ++i) {
        const int r = (tr << 2) + i;
        const float dinv = 1.0f / denF[r];
        float4 sv = make_float4(acc3[i][0] * dinv, acc3[i][1] * dinv,
                                acc3[i][2] * dinv, acc3[i][3] * dinv);
        *(float4*)&ob[(size_t)r * DD + (tc << 2)] = sv;
    }
}

// ---------------------------------------------------------------------------
extern "C" void kernel_launch(void* const* d_in, const int* in_sizes, int n_in,
                              void* d_out, int out_size, void* d_ws, size_t ws_size,
                              hipStream_t stream)
{
    const float* q    = (const float*)d_in[0];
    const float* k    = (const float*)d_in[1];
    const float* v    = (const float*)d_in[2];
    const float* proj = (const float*)d_in[3];
    float* out = (float*)d_out;
    float* ws  = (float*)d_ws;

    float* ctxr = ws;                                   // [32][272][64]
    float* kcr  = ctxr + (size_t)BHX * MP * DD;         // [32][272]
    float* vsm  = kcr + BHX * MP;                       // [32][64]
    float* pmax = vsm + BHX * DD;                       // [1024]
    float* stab = pmax + 1024;                          // [1]

    hipMemsetAsync(ws, 0,
                   ((size_t)BHX * MP * DD + BHX * MP + BHX * DD) * sizeof(float),
                   stream);

    kpass_kernel<<<dim3(32, 32), 256, 0, stream>>>(k, v, proj, ctxr, kcr, vsm, pmax);
    reduce_max_kernel<<<1, 256, 0, stream>>>(pmax, stab, 1024);
    qpass_kernel<<<dim3(64, 32), 256, 0, stream>>>(q, proj, ctxr, kcr, vsm, stab, out);
}

// Round 3
// 278.186 us; speedup vs baseline: 2.6914x; 2.4753x over previous
//
#include <hip/hip_runtime.h>
#include <math.h>

#define BHX 32
#define NN 4096
#define DD 64
#define MM 266
#define MP 272
#define NORMZ 0.35355339059327379f   // 64^-0.25
#define RATIO 0.06131393394849658f   // 266^-0.5
#define EPSV 1e-4f
#define NEG_INF (-3.4e38f)
#define LSTR 72                       // LDS row stride in ushorts (144B, 16B aligned)
#define GSTR 320                      // gctxT row stride in ushorts

typedef __attribute__((ext_vector_type(8))) short bfrag;
typedef __attribute__((ext_vector_type(4))) float f32x4;

#define MFMA(a, b, c) __builtin_amdgcn_mfma_f32_16x16x32_bf16((a), (b), (c), 0, 0, 0)

__device__ inline ushort bf16rne(float x) {
    union { float f; unsigned u; } c; c.f = x;
    unsigned r = c.u + 0x7FFFu + ((c.u >> 16) & 1u);
    return (ushort)(r >> 16);
}
__device__ inline float bf2f(ushort h) {
    union { unsigned u; float f; } c; c.u = ((unsigned)h) << 16;
    return c.f;
}
__device__ inline void splitf(float x, ushort& h, ushort& l) {
    h = bf16rne(x);
    l = bf16rne(x - bf2f(h));
}

// ---------------------------------------------------------------------------
// proj split: proj fp32 [266][64] -> pH/pL bf16 [272][64] (rows >=266 zero)
// ---------------------------------------------------------------------------
__global__ void proj_split(const float* __restrict__ proj,
                           ushort* __restrict__ pH, ushort* __restrict__ pL)
{
    int i = (blockIdx.x * 256 + threadIdx.x) * 4;   // 17*256*4 = 17408 = 272*64
    int m = i >> 6;
    float4 x = (m < MM) ? *(const float4*)(proj + i) : make_float4(0.f, 0.f, 0.f, 0.f);
    ushort h0, l0, h1, l1, h2, l2, h3, l3;
    splitf(x.x, h0, l0); splitf(x.y, h1, l1); splitf(x.z, h2, l2); splitf(x.w, h3, l3);
    *(ushort4*)(pH + i) = make_ushort4(h0, h1, h2, h3);
    *(ushort4*)(pL + i) = make_ushort4(l0, l1, l2, l3);
}

// ---------------------------------------------------------------------------
// vsum[hd][e] = sum_n v[hd][n][e]; grid (8 nchunks, 32 hd)
// ---------------------------------------------------------------------------
__global__ void vsum_kernel(const float* __restrict__ v, float* __restrict__ vsum)
{
    __shared__ float red[4][64];
    const int t = threadIdx.x, hd = blockIdx.y, nc = blockIdx.x;
    const int e = t & 63, g = t >> 6;
    const float* vb = v + ((size_t)hd * NN + nc * 512) * DD;
    float s = 0.f;
    for (int j = 0; j < 128; ++j) s += vb[(j * 4 + g) * DD + e];
    red[g][e] = s;
    __syncthreads();
    if (t < 64) atomicAdd(&vsum[hd * DD + t], red[0][t] + red[1][t] + red[2][t] + red[3][t]);
}

// ---------------------------------------------------------------------------
__global__ void reduce_max_kernel(const float* __restrict__ partmax,
                                  float* __restrict__ stab, int n)
{
    __shared__ float sm[256];
    const int t = threadIdx.x;
    float mx = NEG_INF;
    for (int i = t; i < n; i += 256) mx = fmaxf(mx, partmax[i]);
    sm[t] = mx;
    __syncthreads();
    for (int s = 128; s > 0; s >>= 1) {
        if (t < s) sm[t] = fmaxf(sm[t], sm[t + s]);
        __syncthreads();
    }
    if (t == 0) *stab = sm[0];
}

// ===========================================================================
// k-pass: per 64-row subtile: dd = (NORMZ*k)@proj^T via split-bf16 MFMA,
// u = exp(dd - diag) (unstabilized), block dd-max, ctx partial += u^T@v via
// MFMA, kc partial += colsum(u).  grid (16 nblocks, 32 heads), block 256.
// Wave w owns n-stripe w for dd; m-tile (c*4+w) for ctx (chunk c).
// ===========================================================================
__launch_bounds__(256, 2)
__global__ void kpass(const float* __restrict__ kin, const float* __restrict__ vin,
                      const ushort* __restrict__ pjH, const ushort* __restrict__ pjL,
                      float* __restrict__ ctxP, float* __restrict__ kcP,
                      float* __restrict__ pmax)
{
    __shared__ ushort dataH[64 * LSTR], dataLo[64 * LSTR];  // dd-A source, then uT
    __shared__ ushort vTH[64 * LSTR], vTLo[64 * LSTR];      // [e][n]
    __shared__ ushort r2H[64 * LSTR], r2Lo[64 * LSTR];      // projL chunk [m_l][k]
    __shared__ float diagS[64];
    __shared__ float kcS[MP];
    __shared__ float redS[4];

    const int t = threadIdx.x;
    const int w = t >> 6;
    const int lane = t & 63;
    const int l15 = lane & 15;
    const int q = lane >> 4;
    const int hd = blockIdx.y;
    const int nb = blockIdx.x;

    if (t < 256) kcS[t] = 0.f;
    if (t < 16) kcS[256 + t] = 0.f;

    const f32x4 zf = {0.f, 0.f, 0.f, 0.f};
    f32x4 cacc[4][4];
    f32x4 cacc4 = zf;
    #pragma unroll
    for (int c = 0; c < 4; ++c)
        #pragma unroll
        for (int e = 0; e < 4; ++e) cacc[c][e] = zf;
    float bmaxl = NEG_INF;

    #pragma unroll 1
    for (int st = 0; st < 4; ++st) {
        const int n0 = (nb << 8) + (st << 6);
        __syncthreads();   // protect dataA/vT restage vs last chunk's ctx readers

        // ---- stage dataA (split, +diag) ----
        const float* kb = kin + ((size_t)hd * NN + n0) * DD;
        #pragma unroll
        for (int j = 0; j < 4; ++j) {
            int i = (t + (j << 8)) << 2;
            int r = i >> 6, cc = i & 63;
            float4 x = *(const float4*)(kb + i);
            float x0 = x.x * NORMZ, x1 = x.y * NORMZ, x2 = x.z * NORMZ, x3 = x.w * NORMZ;
            ushort h0, l0, h1, l1, h2, l2, h3, l3;
            splitf(x0, h0, l0); splitf(x1, h1, l1); splitf(x2, h2, l2); splitf(x3, h3, l3);
            *(ushort4*)&dataH[r * LSTR + cc] = make_ushort4(h0, h1, h2, h3);
            *(ushort4*)&dataLo[r * LSTR + cc] = make_ushort4(l0, l1, l2, l3);
            float ss = x0 * x0 + x1 * x1 + x2 * x2 + x3 * x3;
            #pragma unroll
            for (int d = 1; d < 16; d <<= 1) ss += __shfl_xor(ss, d);
            if (l15 == 0) diagS[r] = 0.5f * ss;
        }
        // ---- stage vT (split, transposed) ----
        const float* vb = vin + ((size_t)hd * NN + n0) * DD;
        #pragma unroll
        for (int j = 0; j < 4; ++j) {
            int i = (t + (j << 8)) << 2;
            int n = i >> 6, e = i & 63;
            float4 x = *(const float4*)(vb + i);
            ushort h, l;
            splitf(x.x, h, l); vTH[(e + 0) * LSTR + n] = h; vTLo[(e + 0) * LSTR + n] = l;
            splitf(x.y, h, l); vTH[(e + 1) * LSTR + n] = h; vTLo[(e + 1) * LSTR + n] = l;
            splitf(x.z, h, l); vTH[(e + 2) * LSTR + n] = h; vTLo[(e + 2) * LSTR + n] = l;
            splitf(x.w, h, l); vTH[(e + 3) * LSTR + n] = h; vTLo[(e + 3) * LSTR + n] = l;
        }
        __syncthreads();

        // A-fragments for dd (held in regs; dataA region is reused as uT after)
        bfrag aH[2], aL[2];
        {
            const int row = (w << 4) + l15;
            aH[0] = *(const bfrag*)&dataH[row * LSTR + (q << 3)];
            aH[1] = *(const bfrag*)&dataH[row * LSTR + 32 + (q << 3)];
            aL[0] = *(const bfrag*)&dataLo[row * LSTR + (q << 3)];
            aL[1] = *(const bfrag*)&dataLo[row * LSTR + 32 + (q << 3)];
        }

        #pragma unroll
        for (int c = 0; c < 5; ++c) {
            const int mtiles = (c < 4) ? 4 : 1;
            const int m0 = c << 6;
            // stage projL chunk (r2)
            {
                const int tot = mtiles << 7;   // mtiles*16*64/8
                for (int idx = t; idx < tot; idx += 256) {
                    int i = idx << 3; int r = i >> 6, cc = i & 63;
                    *(uint4*)&r2H[r * LSTR + cc] = *(const uint4*)(pjH + ((m0 + r) << 6) + cc);
                    *(uint4*)&r2Lo[r * LSTR + cc] = *(const uint4*)(pjL + ((m0 + r) << 6) + cc);
                }
            }
            __syncthreads();   // B1: projL ready; prior ctx readers of uT done

            // dd MFMAs
            f32x4 dd4[4];
            #pragma unroll
            for (int mt = 0; mt < 4; ++mt) {
                if (mt >= mtiles) break;
                const int mrow = (mt << 4) + l15;
                bfrag bH0 = *(const bfrag*)&r2H[mrow * LSTR + (q << 3)];
                bfrag bH1 = *(const bfrag*)&r2H[mrow * LSTR + 32 + (q << 3)];
                bfrag bL0 = *(const bfrag*)&r2Lo[mrow * LSTR + (q << 3)];
                bfrag bL1 = *(const bfrag*)&r2Lo[mrow * LSTR + 32 + (q << 3)];
                f32x4 a = zf;
                a = MFMA(aH[0], bL0, a);
                a = MFMA(aH[1], bL1, a);
                a = MFMA(aL[0], bH0, a);
                a = MFMA(aL[1], bH1, a);
                a = MFMA(aH[0], bH0, a);
                a = MFMA(aH[1], bH1, a);
                dd4[mt] = a;
            }
            // exp + max + kc + scatter uT into data region
            #pragma unroll
            for (int mt = 0; mt < 4; ++mt) {
                if (mt >= mtiles) break;
                const int mg = m0 + (mt << 4) + l15;
                const bool valid = (mg < MM);
                ushort uh[4], ul[4];
                float csum = 0.f;
                #pragma unroll
                for (int reg = 0; reg < 4; ++reg) {
                    float dv = dd4[mt][reg];
                    float u = 0.f;
                    if (valid) {
                        bmaxl = fmaxf(bmaxl, dv);
                        u = __expf(dv - diagS[(w << 4) + (q << 2) + reg]);
                    }
                    csum += u;
                    splitf(u, uh[reg], ul[reg]);
                }
                *(ushort4*)&dataH[((mt << 4) + l15) * LSTR + (w << 4) + (q << 2)] =
                    make_ushort4(uh[0], uh[1], uh[2], uh[3]);
                *(ushort4*)&dataLo[((mt << 4) + l15) * LSTR + (w << 4) + (q << 2)] =
                    make_ushort4(ul[0], ul[1], ul[2], ul[3]);
                csum += __shfl_xor(csum, 16);
                csum += __shfl_xor(csum, 32);
                if (q == 0) atomicAdd(&kcS[mg], csum);
            }
            __syncthreads();   // B2: uT complete

            // ctx MFMAs: D[m][e] += uT . v
            if (c < 4) {
                const int mrow = (w << 4) + l15;
                bfrag uH0 = *(const bfrag*)&dataH[mrow * LSTR + (q << 3)];
                bfrag uH1 = *(const bfrag*)&dataH[mrow * LSTR + 32 + (q << 3)];
                bfrag uL0 = *(const bfrag*)&dataLo[mrow * LSTR + (q << 3)];
                bfrag uL1 = *(const bfrag*)&dataLo[mrow * LSTR + 32 + (q << 3)];
                #pragma unroll
                for (int et = 0; et < 4; ++et) {
                    const int erow = (et << 4) + l15;
                    bfrag vH0 = *(const bfrag*)&vTH[erow * LSTR + (q << 3)];
                    bfrag vH1 = *(const bfrag*)&vTH[erow * LSTR + 32 + (q << 3)];
                    bfrag vL0 = *(const bfrag*)&vTLo[erow * LSTR + (q << 3)];
                    bfrag vL1 = *(const bfrag*)&vTLo[erow * LSTR + 32 + (q << 3)];
                    f32x4 a = cacc[c][et];
                    a = MFMA(uH0, vL0, a);
                    a = MFMA(uH1, vL1, a);
                    a = MFMA(uL0, vH0, a);
                    a = MFMA(uL1, vH1, a);
                    a = MFMA(uH0, vH0, a);
                    a = MFMA(uH1, vH1, a);
                    cacc[c][et] = a;
                }
            } else {
                const int mrow = l15;   // m-tile 16 uses rows 0..15 of uT buffer
                bfrag uH0 = *(const bfrag*)&dataH[mrow * LSTR + (q << 3)];
                bfrag uH1 = *(const bfrag*)&dataH[mrow * LSTR + 32 + (q << 3)];
                bfrag uL0 = *(const bfrag*)&dataLo[mrow * LSTR + (q << 3)];
                bfrag uL1 = *(const bfrag*)&dataLo[mrow * LSTR + 32 + (q << 3)];
                const int erow = (w << 4) + l15;   // wave w -> e-tile w
                bfrag vH0 = *(const bfrag*)&vTH[erow * LSTR + (q << 3)];
                bfrag vH1 = *(const bfrag*)&vTH[erow * LSTR + 32 + (q << 3)];
                bfrag vL0 = *(const bfrag*)&vTLo[erow * LSTR + (q << 3)];
                bfrag vL1 = *(const bfrag*)&vTLo[erow * LSTR + 32 + (q << 3)];
                f32x4 a = cacc4;
                a = MFMA(uH0, vL0, a);
                a = MFMA(uH1, vL1, a);
                a = MFMA(uL0, vH0, a);
                a = MFMA(uL1, vH1, a);
                a = MFMA(uH0, vH0, a);
                a = MFMA(uH1, vH1, a);
                cacc4 = a;
            }
        }
    }

    __syncthreads();
    // block dd-max
    {
        float bm = bmaxl;
        #pragma unroll
        for (int d = 1; d < 64; d <<= 1) bm = fmaxf(bm, __shfl_xor(bm, d));
        if (lane == 0) redS[w] = bm;
    }
    __syncthreads();
    if (t == 0) pmax[hd * 16 + nb] = fmaxf(fmaxf(redS[0], redS[1]), fmaxf(redS[2], redS[3]));
    // kc partial
    for (int m = t; m < MP; m += 256) kcP[(size_t)(hd * 16 + nb) * MP + m] = kcS[m];
    // ctx partial (coalesced-ish dword stores)
    float* cp = ctxP + (size_t)(hd * 16 + nb) * MP * DD;
    #pragma unroll
    for (int c = 0; c < 4; ++c) {
        const int mbase = (c << 6) + (w << 4) + (q << 2);
        #pragma unroll
        for (int et = 0; et < 4; ++et)
            #pragma unroll
            for (int reg = 0; reg < 4; ++reg)
                cp[(mbase + reg) * DD + (et << 4) + l15] = cacc[c][et][reg];
    }
    #pragma unroll
    for (int reg = 0; reg < 4; ++reg)
        cp[(256 + (q << 2) + reg) * DD + (w << 4) + l15] = cacc4[reg];
}

// ===========================================================================
// ctx reduce: sum 16 partials, scale by Asc=RATIO*e^-stab, add REPS*vsum,
// split to bf16, write TRANSPOSED gctxT[hd][e][m] (row 64 = kcF, rest zero).
// grid (17 m-tiles, 32 heads)
// ===========================================================================
__global__ void ctx_reduce(const float* __restrict__ ctxP, const float* __restrict__ kcP,
                           const float* __restrict__ vsum, const float* __restrict__ stabp,
                           ushort* __restrict__ gH, ushort* __restrict__ gL)
{
    __shared__ ushort hiT[64][20], loT[64][20];
    const int t = threadIdx.x, mt = blockIdx.x, hd = blockIdx.y;
    const float Asc = RATIO * __expf(-*stabp);
    const float REPS = RATIO * EPSV;
    const int e = t & 63, mq = t >> 6;
    const float vs = vsum[hd * DD + e];
    #pragma unroll
    for (int i = 0; i < 4; ++i) {
        const int ml = mq * 4 + i;
        const int m = mt * 16 + ml;
        float s = 0.f;
        for (int nbk = 0; nbk < 16; ++nbk)
            s += ctxP[((size_t)(hd * 16 + nbk) * MP + m) * DD + e];
        float val = Asc * s + REPS * vs;
        ushort h, l; splitf(val, h, l);
        hiT[e][ml] = h; loT[e][ml] = l;
    }
    __syncthreads();
    {
        const int i = t * 4, e2 = i >> 4, cc = i & 15;
        ushort4 hv = make_ushort4(hiT[e2][cc], hiT[e2][cc + 1], hiT[e2][cc + 2], hiT[e2][cc + 3]);
        ushort4 lv = make_ushort4(loT[e2][cc], loT[e2][cc + 1], loT[e2][cc + 2], loT[e2][cc + 3]);
        *(ushort4*)(gH + ((size_t)hd * 80 + e2) * GSTR + mt * 16 + cc) = hv;
        *(ushort4*)(gL + ((size_t)hd * 80 + e2) * GSTR + mt * 16 + cc) = lv;
    }
    if (t < 16) {
        const int m = mt * 16 + t;
        float s = 0.f;
        for (int nbk = 0; nbk < 16; ++nbk) s += kcP[(size_t)(hd * 16 + nbk) * MP + m];
        float val = Asc * s + ((m < MM) ? REPS * (float)NN : 0.f);
        ushort h, l; splitf(val, h, l);
        gH[((size_t)hd * 80 + 64) * GSTR + m] = h;
        gL[((size_t)hd * 80 + 64) * GSTR + m] = l;
    }
}

// ===========================================================================
// q-pass: per 64-row block: dd via MFMA (regs, all 272 m), rowmax (shfl),
// qp = RATIO*(exp(dd-diag-rowmax)+eps); out = qp@ctxT via MFMA with the
// denominator emerging as column e=64 (ctxT row 64 = kcF).
// grid (64 nblocks, 32 heads), block 256.
// ===========================================================================
__launch_bounds__(256, 2)
__global__ void qpass(const float* __restrict__ qin,
                      const ushort* __restrict__ pjH, const ushort* __restrict__ pjL,
                      const ushort* __restrict__ gH, const ushort* __restrict__ gL,
                      float* __restrict__ outp)
{
    __shared__ ushort dataH[64 * LSTR], dataLo[64 * LSTR];
    __shared__ ushort r2H[64 * LSTR], r2Lo[64 * LSTR];     // projL, then qpA
    __shared__ ushort cbH[80 * LSTR], cbLo[80 * LSTR];     // ctxT chunk [80 e][64 m]
    __shared__ float diagS[64];

    const int t = threadIdx.x;
    const int w = t >> 6;
    const int lane = t & 63;
    const int l15 = lane & 15;
    const int q = lane >> 4;
    const int hd = blockIdx.y;
    const int n0 = blockIdx.x << 6;

    // ---- stage dataA (split, +diag) ----
    const float* qb = qin + ((size_t)hd * NN + n0) * DD;
    #pragma unroll
    for (int j = 0; j < 4; ++j) {
        int i = (t + (j << 8)) << 2;
        int r = i >> 6, cc = i & 63;
        float4 x = *(const float4*)(qb + i);
        float x0 = x.x * NORMZ, x1 = x.y * NORMZ, x2 = x.z * NORMZ, x3 = x.w * NORMZ;
        ushort h0, l0, h1, l1, h2, l2, h3, l3;
        splitf(x0, h0, l0); splitf(x1, h1, l1); splitf(x2, h2, l2); splitf(x3, h3, l3);
        *(ushort4*)&dataH[r * LSTR + cc] = make_ushort4(h0, h1, h2, h3);
        *(ushort4*)&dataLo[r * LSTR + cc] = make_ushort4(l0, l1, l2, l3);
        float ss = x0 * x0 + x1 * x1 + x2 * x2 + x3 * x3;
        #pragma unroll
        for (int d = 1; d < 16; d <<= 1) ss += __shfl_xor(ss, d);
        if (l15 == 0) diagS[r] = 0.5f * ss;
    }
    __syncthreads();

    bfrag aH[2], aL[2];
    {
        const int row = (w << 4) + l15;
        aH[0] = *(const bfrag*)&dataH[row * LSTR + (q << 3)];
        aH[1] = *(const bfrag*)&dataH[row * LSTR + 32 + (q << 3)];
        aL[0] = *(const bfrag*)&dataLo[row * LSTR + (q << 3)];
        aL[1] = *(const bfrag*)&dataLo[row * LSTR + 32 + (q << 3)];
    }

    const f32x4 zf = {0.f, 0.f, 0.f, 0.f};
    f32x4 ddq[17];

    // ---- phase 1: dd for all 272 m ----
    #pragma unroll
    for (int c = 0; c < 5; ++c) {
        const int mtiles = (c < 4) ? 4 : 1;
        const int m0 = c << 6;
        __syncthreads();   // protect r2 restage vs prior dd readers
        {
            const int tot = mtiles << 7;
            for (int idx = t; idx < tot; idx += 256) {
                int i = idx << 3; int r = i >> 6, cc = i & 63;
                *(uint4*)&r2H[r * LSTR + cc] = *(const uint4*)(pjH + ((m0 + r) << 6) + cc);
                *(uint4*)&r2Lo[r * LSTR + cc] = *(const uint4*)(pjL + ((m0 + r) << 6) + cc);
            }
        }
        __syncthreads();
        #pragma unroll
        for (int mt = 0; mt < 4; ++mt) {
            if (mt >= mtiles) break;
            const int mrow = (mt << 4) + l15;
            bfrag bH0 = *(const bfrag*)&r2H[mrow * LSTR + (q << 3)];
            bfrag bH1 = *(const bfrag*)&r2H[mrow * LSTR + 32 + (q << 3)];
            bfrag bL0 = *(const bfrag*)&r2Lo[mrow * LSTR + (q << 3)];
            bfrag bL1 = *(const bfrag*)&r2Lo[mrow * LSTR + 32 + (q << 3)];
            f32x4 a = zf;
            a = MFMA(aH[0], bL0, a);
            a = MFMA(aH[1], bL1, a);
            a = MFMA(aL[0], bH0, a);
            a = MFMA(aL[1], bH1, a);
            a = MFMA(aH[0], bH0, a);
            a = MFMA(aH[1], bH1, a);
            ddq[c * 4 + mt] = a;
        }
    }

    // ---- phase 2: rowmax + qp (registers only) ----
    float rmax[4];
    #pragma unroll
    for (int reg = 0; reg < 4; ++reg) {
        float mx = NEG_INF;
        #pragma unroll
        for (int ti = 0; ti < 17; ++ti) {
            bool valid = (ti < 16) || (l15 < 10);
            if (valid) mx = fmaxf(mx, ddq[ti][reg]);
        }
        #pragma unroll
        for (int d = 1; d < 16; d <<= 1) mx = fmaxf(mx, __shfl_xor(mx, d));
        rmax[reg] = mx;
    }
    #pragma unroll
    for (int ti = 0; ti < 17; ++ti) {
        #pragma unroll
        for (int reg = 0; reg < 4; ++reg) {
            bool valid = (ti < 16) || (l15 < 10);
            float e = 0.f;
            if (valid)
                e = RATIO * (__expf(ddq[ti][reg] - diagS[(w << 4) + (q << 2) + reg] - rmax[reg]) + EPSV);
            ddq[ti][reg] = e;
        }
    }

    // ---- phase 3: out = qp @ ctxT (denominator = col 64) ----
    f32x4 oacc[5];
    #pragma unroll
    for (int et = 0; et < 5; ++et) oacc[et] = zf;

    #pragma unroll
    for (int c = 0; c < 5; ++c) {
        const int mtiles = (c < 4) ? 4 : 1;
        __syncthreads();   // protect cb restage (and first-iter r2 scatter) vs prior readers
        // stage ctxT chunk [80 e][64 m]
        {
            for (int idx = t; idx < 640; idx += 256) {
                int i = idx << 3; int e = i >> 6, mm = i & 63;
                *(uint4*)&cbH[e * LSTR + mm] =
                    *(const uint4*)(gH + ((size_t)hd * 80 + e) * GSTR + (c << 6) + mm);
                *(uint4*)&cbLo[e * LSTR + mm] =
                    *(const uint4*)(gL + ((size_t)hd * 80 + e) * GSTR + (c << 6) + mm);
            }
        }
        // scatter qpA (own rows only)
        #pragma unroll
        for (int mt = 0; mt < 4; ++mt) {
            if (mt >= mtiles) break;
            const int ml = (mt << 4) + l15;
            #pragma unroll
            for (int reg = 0; reg < 4; ++reg) {
                ushort h, l; splitf(ddq[c * 4 + mt][reg], h, l);
                r2H[((w << 4) + (q << 2) + reg) * LSTR + ml] = h;
                r2Lo[((w << 4) + (q << 2) + reg) * LSTR + ml] = l;
            }
        }
        if (c == 4) {   // zero-pad qpA cols 16..31 (K-step padding)
            const int rown = (w << 4) + l15;
            *(ushort4*)&r2H[rown * LSTR + 16 + (q << 2)] = make_ushort4(0, 0, 0, 0);
            *(ushort4*)&r2Lo[rown * LSTR + 16 + (q << 2)] = make_ushort4(0, 0, 0, 0);
        }
        __syncthreads();
        // MFMAs: A = qpA rows (own), B = cb
        const int arow = (w << 4) + l15;
        bfrag pH0 = *(const bfrag*)&r2H[arow * LSTR + (q << 3)];
        bfrag pL0 = *(const bfrag*)&r2Lo[arow * LSTR + (q << 3)];
        bfrag pH1, pL1;
        if (c < 4) {
            pH1 = *(const bfrag*)&r2H[arow * LSTR + 32 + (q << 3)];
            pL1 = *(const bfrag*)&r2Lo[arow * LSTR + 32 + (q << 3)];
        }
        #pragma unroll
        for (int et = 0; et < 5; ++et) {
            const int erow = (et << 4) + l15;
            bfrag cH0 = *(const bfrag*)&cbH[erow * LSTR + (q << 3)];
            bfrag cL0 = *(const bfrag*)&cbLo[erow * LSTR + (q << 3)];
            f32x4 a = oacc[et];
            a = MFMA(pH0, cL0, a);
            a = MFMA(pL0, cH0, a);
            a = MFMA(pH0, cH0, a);
            if (c < 4) {
                bfrag cH1 = *(const bfrag*)&cbH[erow * LSTR + 32 + (q << 3)];
                bfrag cL1 = *(const bfrag*)&cbLo[erow * LSTR + 32 + (q << 3)];
                a = MFMA(pH1, cL1, a);
                a = MFMA(pL1, cH1, a);
                a = MFMA(pH1, cH1, a);
            }
            oacc[et] = a;
        }
    }

    // ---- epilogue: divide by denominator (col e=64 -> tile 4, l15==0) ----
    float dinv[4];
    #pragma unroll
    for (int reg = 0; reg < 4; ++reg) {
        float den = __shfl(oacc[4][reg], lane & 48);
        dinv[reg] = 1.f / den;
    }
    float* ob = outp + ((size_t)hd * NN + n0) * DD;
    #pragma unroll
    for (int et = 0; et < 4; ++et)
        #pragma unroll
        for (int reg = 0; reg < 4; ++reg)
            ob[((w << 4) + (q << 2) + reg) * DD + (et << 4) + l15] = oacc[et][reg] * dinv[reg];
}

// ---------------------------------------------------------------------------
extern "C" void kernel_launch(void* const* d_in, const int* in_sizes, int n_in,
                              void* d_out, int out_size, void* d_ws, size_t ws_size,
                              hipStream_t stream)
{
    const float* q = (const float*)d_in[0];
    const float* k = (const float*)d_in[1];
    const float* v = (const float*)d_in[2];
    const float* proj = (const float*)d_in[3];
    float* out = (float*)d_out;
    char* ws = (char*)d_ws;

    ushort* gH = (ushort*)(ws);                        // 32*80*320*2 = 1,638,400 B
    ushort* gL = (ushort*)(ws + 1638400);              // 1,638,400 B
    float* vsm = (float*)(ws + 3276800);               // 8,192 B
    ushort* pH = (ushort*)(ws + 3284992);              // 34,816 B
    ushort* pL = (ushort*)(ws + 3319808);              // 34,816 B
    float* ctxP = (float*)(ws + 3354624);              // 512*272*64*4 = 35,651,584 B
    float* kcP = (float*)(ws + 39006208);              // 557,056 B
    float* pmax = (float*)(ws + 39563264);             // 2,048 B
    float* stab = (float*)(ws + 39565312);             // 4 B

    hipMemsetAsync(ws, 0, 3284992, stream);            // gH, gL, vsum

    proj_split<<<dim3(17), 256, 0, stream>>>(proj, pH, pL);
    vsum_kernel<<<dim3(8, 32), 256, 0, stream>>>(v, vsm);
    kpass<<<dim3(16, 32), 256, 0, stream>>>(k, v, pH, pL, ctxP, kcP, pmax);
    reduce_max_kernel<<<1, 256, 0, stream>>>(pmax, stab, 512);
    ctx_reduce<<<dim3(17, 32), 256, 0, stream>>>(ctxP, kcP, vsm, stab, gH, gL);
    qpass<<<dim3(64, 32), 256, 0, stream>>>(q, pH, pL, gH, gL, out);
}